// Round 5
// baseline (393.829 us; speedup 1.0000x reference)
//
#include <hip/hip_runtime.h>
#include <hip/hip_bf16.h>

// GraphSAGE 2-layer forward on MI355X — round 5.
// Key idea: XCD-sliced feature layout. All feature tensors live as
// T[8][N][16] bf16 (slice s = cols 16s..16s+15, 32 B/row). Aggregation blocks
// pick slice = blockIdx&7 so each XCD's gathers hit only a 1.6 MB region ->
// L2-resident. CSR fill partitions dst ranges by blockIdx&7 for the same
// reason (round 3/4 showed 50 MB WRITE_SIZE from cross-XCD line ping-pong).
// MFMA GEMMs read the sliced layout directly (full-line coalesced fragments).

#define BLK 256

typedef __attribute__((ext_vector_type(8))) short short8;
typedef __attribute__((ext_vector_type(4))) float f32x4;

__device__ inline unsigned short f2bf(float f) {
    unsigned int u = __builtin_bit_cast(unsigned int, f);
    u += 0x7fffu + ((u >> 16) & 1u);  // RNE (inputs finite)
    return (unsigned short)(u >> 16);
}
__device__ inline float bf2f(unsigned short h) {
    return __builtin_bit_cast(float, ((unsigned int)h) << 16);
}

// ---------------- CSR build ----------------

__global__ __launch_bounds__(BLK) void deg_count_kernel(const int* __restrict__ dst,
                                                        int E, int* __restrict__ deg) {
    int e = blockIdx.x * BLK + threadIdx.x;
    if (e < E) atomicAdd(&deg[dst[e]], 1);
}

__global__ __launch_bounds__(BLK) void partial_sum_kernel(const int* __restrict__ deg,
                                                          int n, int* __restrict__ partials) {
    __shared__ int s[BLK];
    int t = threadIdx.x;
    int idx = blockIdx.x * BLK + t;
    s[t] = (idx < n) ? deg[idx] : 0;
    __syncthreads();
    for (int o = BLK / 2; o > 0; o >>= 1) {
        if (t < o) s[t] += s[t + o];
        __syncthreads();
    }
    if (t == 0) partials[blockIdx.x] = s[0];
}

__global__ __launch_bounds__(BLK) void scan_partials_kernel(int* __restrict__ partials, int n) {
    __shared__ int s[BLK];
    int t = threadIdx.x;
    int v = (t < n) ? partials[t] : 0;
    s[t] = v;
    __syncthreads();
    int sum = v;
    for (int o = 1; o < BLK; o <<= 1) {
        int other = (t >= o) ? s[t - o] : 0;
        __syncthreads();
        sum += other;
        s[t] = sum;
        __syncthreads();
    }
    if (t < n) partials[t] = sum - v;  // exclusive
}

__global__ __launch_bounds__(BLK) void chunk_scan_kernel(const int* __restrict__ deg,
                                                         const int* __restrict__ partials,
                                                         int n, int* __restrict__ row_start) {
    __shared__ int s[BLK];
    int t = threadIdx.x;
    int idx = blockIdx.x * BLK + t;
    int v = (idx < n) ? deg[idx] : 0;
    s[t] = v;
    __syncthreads();
    int sum = v;
    for (int o = 1; o < BLK; o <<= 1) {
        int other = (t >= o) ? s[t - o] : 0;
        __syncthreads();
        sum += other;
        s[t] = sum;
        __syncthreads();
    }
    if (idx < n) row_start[idx] = (sum - v) + partials[blockIdx.x];
}

// XCD-partitioned fill: blockIdx&7 owns a dst octant (-> one XCD via the %8
// round-robin block->XCD mapping), so all csr/cursor writes for that octant
// stay in one L2 and merge before writeback.
__global__ __launch_bounds__(BLK) void fill_xcd_kernel(const int* __restrict__ src,
                                                       const int* __restrict__ dst, int E,
                                                       const int* __restrict__ row_start,
                                                       int* __restrict__ cursor,
                                                       int* __restrict__ csr_src,
                                                       int range, int CH) {
    const int oct = blockIdx.x & 7;
    const int chunk = blockIdx.x >> 3;
    const int lo = oct * range, hi = lo + range;
    int e0 = chunk * CH;
    int e1 = min(E, e0 + CH);
    for (int e = e0 + threadIdx.x; e < e1; e += BLK) {
        int d = dst[e];
        if (d >= lo && d < hi) {
            int pos = atomicAdd(&cursor[d], 1);
            csr_src[row_start[d] + pos] = src[e];
        }
    }
}

// ---------------- x f32 [N][128] -> sliced bf16 xT[8][N][16] ----------------

__global__ __launch_bounds__(BLK) void x_prep_kernel(const float* __restrict__ x,
                                                     unsigned short* __restrict__ xT,
                                                     int N) {
    int node = blockIdx.x * BLK + threadIdx.x;
    int slice = blockIdx.y;
    if (node >= N) return;
    const float4* xp = (const float4*)(x + (size_t)node * 128 + slice * 16);
    unsigned int u[8];
#pragma unroll
    for (int q = 0; q < 4; ++q) {
        float4 v = xp[q];
        u[q * 2]     = (unsigned int)f2bf(v.x) | ((unsigned int)f2bf(v.y) << 16);
        u[q * 2 + 1] = (unsigned int)f2bf(v.z) | ((unsigned int)f2bf(v.w) << 16);
    }
    uint4* o = (uint4*)(xT + ((size_t)slice * N + node) * 16);
    o[0] = make_uint4(u[0], u[1], u[2], u[3]);
    o[1] = make_uint4(u[4], u[5], u[6], u[7]);
}

// ---------------- weight packing (unchanged layout) ----------------
// P[((kb*(Ncol/16)+n16)*64 + lane)*8 + j] = W[kb*32 + (lane>>4)*8 + j][n16*16 + (lane&15)]

__global__ __launch_bounds__(BLK) void pack_all_w_kernel(const float* __restrict__ W1l,
                                                         const float* __restrict__ W1r,
                                                         const float* __restrict__ W2l,
                                                         const float* __restrict__ W2r,
                                                         unsigned short* __restrict__ P1l,
                                                         unsigned short* __restrict__ P1r,
                                                         unsigned short* __restrict__ P2l,
                                                         unsigned short* __restrict__ P2r) {
    int t = blockIdx.x * BLK + threadIdx.x;
    const float* W;
    unsigned short* P;
    int Ncol, local;
    if (t < 16384)      { W = W1l; P = P1l; Ncol = 128; local = t; }
    else if (t < 32768) { W = W1r; P = P1r; Ncol = 128; local = t - 16384; }
    else if (t < 40960) { W = W2l; P = P2l; Ncol = 64;  local = t - 32768; }
    else if (t < 49152) { W = W2r; P = P2r; Ncol = 64;  local = t - 40960; }
    else return;
    int j = local & 7;
    int lane = (local >> 3) & 63;
    int rest = local >> 9;
    int nt = Ncol >> 4;
    int n16 = rest % nt, kb = rest / nt;
    int k = kb * 32 + (lane >> 4) * 8 + j;
    int c = n16 * 16 + (lane & 15);
    P[local] = f2bf(W[(size_t)k * Ncol + c]);
}

// ---------------- sliced mean aggregation ----------------
// One wave handles UN nodes for one slice. Lanes: es=lane>>3 (edge sub),
// cu=lane&7 (uint col in slice). 8 edges gathered per wave-load; per-edge
// weight inv(=1/deg) folded into fmaf (no tail divergence, no final divide).

__global__ __launch_bounds__(BLK) void agg_sliced_kernel(const unsigned short* __restrict__ fT,
                                                         const int* __restrict__ row_start,
                                                         const int* __restrict__ deg,
                                                         const int* __restrict__ csr_src,
                                                         unsigned short* __restrict__ aT,
                                                         int N) {
    const int wave = threadIdx.x >> 6, lane = threadIdx.x & 63;
    const int slice = blockIdx.x & 7;
    const int g = blockIdx.x >> 3;
    const int cu = lane & 7;
    const int es = lane >> 3;
    const unsigned int* xs = (const unsigned int*)(fT + (size_t)slice * N * 16);  // [N][8]
    unsigned int* as = (unsigned int*)(aT + (size_t)slice * N * 16);

    const int UN = 8;
    int node0 = (g * 4 + wave) * UN;
    for (int u = 0; u < UN; ++u) {
        int node = node0 + u;
        if (node >= N) return;
        int start = row_start[node];
        int cnt = deg[node];
        float inv = 1.0f / fmaxf((float)cnt, 1.0f);
        float s0 = 0.f, s1 = 0.f;
        for (int e0 = 0; e0 < cnt; e0 += 8) {
            int ee = e0 + es;
            float w = (ee < cnt) ? inv : 0.0f;
            int esel = (ee < cnt) ? ee : (cnt - 1);
            int idx = csr_src[start + esel];
            unsigned int v = xs[(size_t)idx * 8 + cu];
            s0 = fmaf(bf2f((unsigned short)v), w, s0);
            s1 = fmaf(bf2f((unsigned short)(v >> 16)), w, s1);
        }
#pragma unroll
        for (int m = 8; m <= 32; m <<= 1) {
            s0 += __shfl_xor(s0, m);
            s1 += __shfl_xor(s1, m);
        }
        if (es == 0)
            as[(size_t)node * 8 + cu] = (unsigned int)f2bf(s0) | ((unsigned int)f2bf(s1) << 16);
    }
}

// ---------------- MFMA dual GEMM on sliced A operands ----------------
// A1,A2: sliced [8][M][16] bf16. out: OUTMODE 0 = f32 row-major [M][NCOL],
// OUTMODE 1 = bf16 sliced [NCOL/16][M][16].
// A-frag k-base = kgrp*8 + kb*32 -> slice = 2*kb + (kgrp>>1), off = (kgrp&1)*8.

template <int NCOL, bool RELU, int OUTMODE>
__global__ __launch_bounds__(BLK) void gemm_dual_T_kernel(const unsigned short* __restrict__ A1,
                                                          const unsigned short* __restrict__ A2,
                                                          const unsigned short* __restrict__ Pl,
                                                          const unsigned short* __restrict__ Pr,
                                                          const float* __restrict__ bias,
                                                          void* __restrict__ outp, int M) {
    constexpr int NT = NCOL / 16;
    const int wave = threadIdx.x >> 6, lane = threadIdx.x & 63;
    const int r0 = blockIdx.x * 128 + wave * 32;
    const int arow = lane & 15, kgrp = lane >> 4;
    const int kg2 = kgrp >> 1, off8 = (kgrp & 1) * 8;

    f32x4 acc[2][NT];
#pragma unroll
    for (int h = 0; h < 2; h++)
#pragma unroll
        for (int n = 0; n < NT; n++) acc[h][n] = (f32x4){0.f, 0.f, 0.f, 0.f};

    const int ra = min(r0 + arow, M - 1);
    const int rb = min(r0 + 16 + arow, M - 1);
    const size_t sstride = (size_t)M * 16;  // shorts per slice plane

#pragma unroll
    for (int mat = 0; mat < 2; ++mat) {
        const unsigned short* A = mat ? A2 : A1;
        const unsigned short* P = mat ? Pr : Pl;
        const unsigned short* Aa = A + (size_t)kg2 * sstride + (size_t)ra * 16 + off8;
        const unsigned short* Ab = A + (size_t)kg2 * sstride + (size_t)rb * 16 + off8;
#pragma unroll
        for (int kb = 0; kb < 4; ++kb) {
            short8 afa = *(const short8*)(Aa + (size_t)kb * 2 * sstride);
            short8 afb = *(const short8*)(Ab + (size_t)kb * 2 * sstride);
            const unsigned short* Pk = P + (size_t)kb * NT * 512 + lane * 8;
#pragma unroll
            for (int n = 0; n < NT; ++n) {
                short8 wf = *(const short8*)(Pk + n * 512);
                acc[0][n] = __builtin_amdgcn_mfma_f32_16x16x32_bf16(afa, wf, acc[0][n], 0, 0, 0);
                acc[1][n] = __builtin_amdgcn_mfma_f32_16x16x32_bf16(afb, wf, acc[1][n], 0, 0, 0);
            }
        }
    }

    // D layout: col = n*16 + arow, row = r0 + h*16 + kgrp*4 + i
#pragma unroll
    for (int n = 0; n < NT; ++n) {
        int col = n * 16 + arow;
        float bv = bias[col];
#pragma unroll
        for (int h = 0; h < 2; ++h) {
#pragma unroll
            for (int i = 0; i < 4; ++i) {
                int row = r0 + h * 16 + kgrp * 4 + i;
                if (row < M) {
                    float v = acc[h][n][i] + bv;
                    if (RELU) v = fmaxf(v, 0.f);
                    if (OUTMODE == 1)
                        ((unsigned short*)outp)[(size_t)n * M * 16 + (size_t)row * 16 + arow] =
                            f2bf(v);
                    else
                        ((float*)outp)[(size_t)row * NCOL + col] = v;
                }
            }
        }
    }
}

// ---------------- launch ----------------

extern "C" void kernel_launch(void* const* d_in, const int* in_sizes, int n_in,
                              void* d_out, int out_size, void* d_ws, size_t ws_size,
                              hipStream_t stream) {
    const float* x   = (const float*)d_in[0];
    const int*   ei  = (const int*)d_in[1];
    const float* W1l = (const float*)d_in[2];
    const float* W1r = (const float*)d_in[3];
    const float* b1  = (const float*)d_in[4];
    const float* W2l = (const float*)d_in[5];
    const float* W2r = (const float*)d_in[6];
    const float* b2  = (const float*)d_in[7];
    float* out = (float*)d_out;

    const int N = in_sizes[0] / 128;  // 50000
    const int E = in_sizes[1] / 2;    // 800000
    const int* src = ei;
    const int* dst = ei + E;

    char* ws = (char*)d_ws;
    size_t off = 0;
    auto carve = [&](size_t bytes) {
        void* p = ws + off;
        off += (bytes + 255) & ~(size_t)255;
        return p;
    };
    int* deg       = (int*)carve((size_t)2 * N * 4);  // deg + cursor, one memset
    int* cursor    = deg + N;
    int* row_start = (int*)carve((size_t)N * 4);
    int* partials  = (int*)carve(256 * 4);
    int* csr_src   = (int*)carve((size_t)E * 4);
    unsigned short* xT   = (unsigned short*)carve((size_t)8 * N * 16 * 2);  // [8][N][16]
    unsigned short* hT   = (unsigned short*)carve((size_t)8 * N * 16 * 2);
    unsigned short* aggT = (unsigned short*)carve((size_t)8 * N * 16 * 2);
    unsigned short* P1l  = (unsigned short*)carve(128 * 128 * 2);
    unsigned short* P1r  = (unsigned short*)carve(128 * 128 * 2);
    unsigned short* P2l  = (unsigned short*)carve(128 * 64 * 2);
    unsigned short* P2r  = (unsigned short*)carve(128 * 64 * 2);

    hipMemsetAsync(deg, 0, (size_t)2 * N * 4, stream);

    // x -> sliced bf16
    dim3 prepGrid((N + BLK - 1) / BLK, 8);
    x_prep_kernel<<<prepGrid, BLK, 0, stream>>>(x, xT, N);
    pack_all_w_kernel<<<192, BLK, 0, stream>>>(W1l, W1r, W2l, W2r, P1l, P1r, P2l, P2r);

    // CSR build
    const int nchunk = (N + BLK - 1) / BLK;  // 196 (<=256)
    deg_count_kernel<<<(E + BLK - 1) / BLK, BLK, 0, stream>>>(dst, E, deg);
    partial_sum_kernel<<<nchunk, BLK, 0, stream>>>(deg, N, partials);
    scan_partials_kernel<<<1, BLK, 0, stream>>>(partials, nchunk);
    chunk_scan_kernel<<<nchunk, BLK, 0, stream>>>(deg, partials, N, row_start);

    const int range = (N + 7) / 8;          // 6250
    const int NCHUNKS = 512;
    const int CH = (E + NCHUNKS - 1) / NCHUNKS;
    fill_xcd_kernel<<<8 * NCHUNKS, BLK, 0, stream>>>(src, dst, E, row_start, cursor,
                                                     csr_src, range, CH);

    // agg grid: slice = blockIdx&7, 4 waves/block, 8 nodes/wave
    const int aggGrid = 8 * ((N + 31) / 32);
    const int gemmGrid = (N + 127) / 128;

    // layer 1: hT = relu(agg(x)@W1l + b1 + x@W1r)   (sliced bf16)
    agg_sliced_kernel<<<aggGrid, BLK, 0, stream>>>(xT, row_start, deg, csr_src, aggT, N);
    gemm_dual_T_kernel<128, true, 1><<<gemmGrid, BLK, 0, stream>>>(aggT, xT, P1l, P1r, b1, hT, N);
    // layer 2: out = agg(h)@W2l + b2 + h@W2r        (f32 row-major)
    agg_sliced_kernel<<<aggGrid, BLK, 0, stream>>>(hT, row_start, deg, csr_src, aggT, N);
    gemm_dual_T_kernel<64, false, 0><<<gemmGrid, BLK, 0, stream>>>(aggT, hT, P2l, P2r, b2, out, N);
}

// Round 8
// 265.479 us; speedup vs baseline: 1.4835x; 1.4835x over previous
//
#include <hip/hip_runtime.h>
#include <hip/hip_bf16.h>

// GraphSAGE 2-layer forward on MI355X — round 8 (round-6/7 resubmit; both
// prior attempts died to infra: container failure, then GPU acquisition
// timeout — kernel itself never executed).
// Row-major bf16 data path + MFMA GEMMs with scalarized-gather aggregation:
// neighbor index -> SGPR via readlane, row address formed on the SALU, 16
// independent gathers in flight per wave (rounds 2/3/5 showed agg is
// latency/MLP-bound, not bandwidth-bound). CSR fill XCD-partitioned.

#define BLK 256

typedef __attribute__((ext_vector_type(8))) short short8;
typedef __attribute__((ext_vector_type(4))) float f32x4;

__device__ inline unsigned short f2bf(float f) {
    unsigned int u = __builtin_bit_cast(unsigned int, f);
    u += 0x7fffu + ((u >> 16) & 1u);  // RNE (inputs finite)
    return (unsigned short)(u >> 16);
}
__device__ inline float bf2f(unsigned short h) {
    return __builtin_bit_cast(float, ((unsigned int)h) << 16);
}

// ---------------- CSR build ----------------

__global__ __launch_bounds__(BLK) void deg_count_kernel(const int* __restrict__ dst,
                                                        int E, int* __restrict__ deg) {
    int e = blockIdx.x * BLK + threadIdx.x;
    if (e < E) atomicAdd(&deg[dst[e]], 1);
}

__global__ __launch_bounds__(BLK) void partial_sum_kernel(const int* __restrict__ deg,
                                                          int n, int* __restrict__ partials) {
    __shared__ int s[BLK];
    int t = threadIdx.x;
    int idx = blockIdx.x * BLK + t;
    s[t] = (idx < n) ? deg[idx] : 0;
    __syncthreads();
    for (int o = BLK / 2; o > 0; o >>= 1) {
        if (t < o) s[t] += s[t + o];
        __syncthreads();
    }
    if (t == 0) partials[blockIdx.x] = s[0];
}

__global__ __launch_bounds__(BLK) void scan_partials_kernel(int* __restrict__ partials, int n) {
    __shared__ int s[BLK];
    int t = threadIdx.x;
    int v = (t < n) ? partials[t] : 0;
    s[t] = v;
    __syncthreads();
    int sum = v;
    for (int o = 1; o < BLK; o <<= 1) {
        int other = (t >= o) ? s[t - o] : 0;
        __syncthreads();
        sum += other;
        s[t] = sum;
        __syncthreads();
    }
    if (t < n) partials[t] = sum - v;  // exclusive
}

__global__ __launch_bounds__(BLK) void chunk_scan_kernel(const int* __restrict__ deg,
                                                         const int* __restrict__ partials,
                                                         int n, int* __restrict__ row_start) {
    __shared__ int s[BLK];
    int t = threadIdx.x;
    int idx = blockIdx.x * BLK + t;
    int v = (idx < n) ? deg[idx] : 0;
    s[t] = v;
    __syncthreads();
    int sum = v;
    for (int o = 1; o < BLK; o <<= 1) {
        int other = (t >= o) ? s[t - o] : 0;
        __syncthreads();
        sum += other;
        s[t] = sum;
        __syncthreads();
    }
    if (idx < n) row_start[idx] = (sum - v) + partials[blockIdx.x];
}

// XCD-partitioned fill: blockIdx&7 owns a dst octant so csr/cursor writes for
// that octant stay in one XCD's L2 and merge before writeback.
__global__ __launch_bounds__(BLK) void fill_xcd_kernel(const int* __restrict__ src,
                                                       const int* __restrict__ dst, int E,
                                                       const int* __restrict__ row_start,
                                                       int* __restrict__ cursor,
                                                       int* __restrict__ csr_src,
                                                       int range, int CH) {
    const int oct = blockIdx.x & 7;
    const int chunk = blockIdx.x >> 3;
    const int lo = oct * range, hi = lo + range;
    int e0 = chunk * CH;
    int e1 = min(E, e0 + CH);
    for (int e = e0 + threadIdx.x; e < e1; e += BLK) {
        int d = dst[e];
        if (d >= lo && d < hi) {
            int pos = atomicAdd(&cursor[d], 1);
            csr_src[row_start[d] + pos] = src[e];
        }
    }
}

// ---------------- conversions / weight packing ----------------

__global__ __launch_bounds__(BLK) void f32_to_bf16_kernel(const float* __restrict__ in,
                                                          unsigned short* __restrict__ out,
                                                          int nquad) {
    int i = blockIdx.x * BLK + threadIdx.x;
    if (i >= nquad) return;
    float4 v = ((const float4*)in)[i];
    ushort4 o;
    o.x = f2bf(v.x); o.y = f2bf(v.y); o.z = f2bf(v.z); o.w = f2bf(v.w);
    ((ushort4*)out)[i] = o;
}

// P[((kb*(Ncol/16)+n16)*64 + lane)*8 + j] = W[kb*32 + (lane>>4)*8 + j][n16*16 + (lane&15)]
__global__ __launch_bounds__(BLK) void pack_all_w_kernel(const float* __restrict__ W1l,
                                                         const float* __restrict__ W1r,
                                                         const float* __restrict__ W2l,
                                                         const float* __restrict__ W2r,
                                                         unsigned short* __restrict__ P1l,
                                                         unsigned short* __restrict__ P1r,
                                                         unsigned short* __restrict__ P2l,
                                                         unsigned short* __restrict__ P2r) {
    int t = blockIdx.x * BLK + threadIdx.x;
    const float* W;
    unsigned short* P;
    int Ncol, local;
    if (t < 16384)      { W = W1l; P = P1l; Ncol = 128; local = t; }
    else if (t < 32768) { W = W1r; P = P1r; Ncol = 128; local = t - 16384; }
    else if (t < 40960) { W = W2l; P = P2l; Ncol = 64;  local = t - 32768; }
    else if (t < 49152) { W = W2r; P = P2r; Ncol = 64;  local = t - 40960; }
    else return;
    int j = local & 7;
    int lane = (local >> 3) & 63;
    int rest = local >> 9;
    int nt = Ncol >> 4;
    int n16 = rest % nt, kb = rest / nt;
    int k = kb * 32 + (lane >> 4) * 8 + j;
    int c = n16 * 16 + (lane & 15);
    P[local] = f2bf(W[(size_t)k * Ncol + c]);
}

// ---------------- scalarized-gather mean aggregation ----------------
// One wave per node, 64 lanes cover one 256B bf16 row (1 uint = 2 bf16/lane).
// Neighbor index -> SGPR (readlane, wave-uniform slot) -> scalar row base ->
// 16 independent global loads in flight. Masked-16 chunks: slots past cnt
// re-read edge m-1's row (same cache lines, ~free) with weight 0; 1/deg is
// folded into the fmaf so there is no final divide.

__global__ __launch_bounds__(BLK) void agg_mlp_kernel(const unsigned short* __restrict__ feat,
                                                      const int* __restrict__ row_start,
                                                      const int* __restrict__ deg,
                                                      const int* __restrict__ csr_src,
                                                      unsigned short* __restrict__ out,
                                                      int N, int E) {
    const int wave = threadIdx.x >> 6, lane = threadIdx.x & 63;
    const int node = blockIdx.x * (BLK / 64) + wave;
    if (node >= N) return;
    const int start = __builtin_amdgcn_readfirstlane(row_start[node]);
    int cnt = __builtin_amdgcn_readfirstlane(deg[node]);
    cnt = min(cnt, E);  // defensive bound (deg rebuilt every launch; clamp anyway)
    const float inv = 1.0f / fmaxf((float)cnt, 1.0f);
    const unsigned int* fp = (const unsigned int*)feat;  // 64 uints per row

    float a0 = 0.f, a1 = 0.f;
    for (int base = 0; base < cnt; base += 64) {
        int m = cnt - base;
        if (m > 64) m = 64;
        int idxv = csr_src[start + base + (lane < m ? lane : m - 1)];
        for (int e = 0; e < m; e += 16) {
            unsigned int v[16];
#pragma unroll
            for (int j = 0; j < 16; j++) {
                int ee = e + j;
                int sl = ee < m ? ee : m - 1;                       // wave-uniform slot
                int s = __builtin_amdgcn_readlane(idxv, sl);        // SGPR index
                v[j] = fp[(size_t)s * 64 + lane];                   // saddr + lane offset
            }
#pragma unroll
            for (int j = 0; j < 16; j++) {
                float w = (e + j < m) ? inv : 0.0f;                 // wave-uniform weight
                a0 = fmaf(bf2f((unsigned short)v[j]), w, a0);
                a1 = fmaf(bf2f((unsigned short)(v[j] >> 16)), w, a1);
            }
        }
    }
    ((unsigned int*)out)[(size_t)node * 64 + lane] =
        (unsigned int)f2bf(a0) | ((unsigned int)f2bf(a1) << 16);
}

// ---------------- MFMA dual GEMM: out = A1@Pl + A2@Pr + bias ----------------
// A-frag: lane holds row=lane&15 (+16), k=(lane>>4)*8+j contiguous 16B.
// D-frag: col=lane&15, row=(lane>>4)*4+i.

template <int NCOL, bool RELU, bool OUT_BF16>
__global__ __launch_bounds__(BLK) void gemm_dual_kernel(const unsigned short* __restrict__ A1,
                                                        const unsigned short* __restrict__ A2,
                                                        const unsigned short* __restrict__ Pl,
                                                        const unsigned short* __restrict__ Pr,
                                                        const float* __restrict__ bias,
                                                        void* __restrict__ outp, int M) {
    constexpr int NT = NCOL / 16;
    const int wave = threadIdx.x >> 6, lane = threadIdx.x & 63;
    const int r0 = blockIdx.x * 128 + wave * 32;
    const int arow = lane & 15, kgrp = lane >> 4;

    f32x4 acc[2][NT];
#pragma unroll
    for (int h = 0; h < 2; h++)
#pragma unroll
        for (int n = 0; n < NT; n++) acc[h][n] = (f32x4){0.f, 0.f, 0.f, 0.f};

    const int ra = min(r0 + arow, M - 1);
    const int rb = min(r0 + 16 + arow, M - 1);

#pragma unroll
    for (int mat = 0; mat < 2; ++mat) {
        const unsigned short* A = mat ? A2 : A1;
        const unsigned short* P = mat ? Pr : Pl;
        const unsigned short* Aa = A + (size_t)ra * 128 + kgrp * 8;
        const unsigned short* Ab = A + (size_t)rb * 128 + kgrp * 8;
#pragma unroll
        for (int kb = 0; kb < 4; ++kb) {
            short8 afa = *(const short8*)(Aa + kb * 32);
            short8 afb = *(const short8*)(Ab + kb * 32);
            const unsigned short* Pk = P + (size_t)kb * NT * 512 + lane * 8;
#pragma unroll
            for (int n = 0; n < NT; ++n) {
                short8 wf = *(const short8*)(Pk + n * 512);
                acc[0][n] = __builtin_amdgcn_mfma_f32_16x16x32_bf16(afa, wf, acc[0][n], 0, 0, 0);
                acc[1][n] = __builtin_amdgcn_mfma_f32_16x16x32_bf16(afb, wf, acc[1][n], 0, 0, 0);
            }
        }
    }

#pragma unroll
    for (int n = 0; n < NT; ++n) {
        int col = n * 16 + arow;
        float bv = bias[col];
#pragma unroll
        for (int h = 0; h < 2; ++h) {
#pragma unroll
            for (int i = 0; i < 4; ++i) {
                int row = r0 + h * 16 + kgrp * 4 + i;
                if (row < M) {
                    float v = acc[h][n][i] + bv;
                    if (RELU) v = fmaxf(v, 0.f);
                    if (OUT_BF16)
                        ((unsigned short*)outp)[(size_t)row * NCOL + col] = f2bf(v);
                    else
                        ((float*)outp)[(size_t)row * NCOL + col] = v;
                }
            }
        }
    }
}

// ---------------- launch ----------------

extern "C" void kernel_launch(void* const* d_in, const int* in_sizes, int n_in,
                              void* d_out, int out_size, void* d_ws, size_t ws_size,
                              hipStream_t stream) {
    const float* x   = (const float*)d_in[0];
    const int*   ei  = (const int*)d_in[1];
    const float* W1l = (const float*)d_in[2];
    const float* W1r = (const float*)d_in[3];
    const float* b1  = (const float*)d_in[4];
    const float* W2l = (const float*)d_in[5];
    const float* W2r = (const float*)d_in[6];
    const float* b2  = (const float*)d_in[7];
    float* out = (float*)d_out;

    const int N = in_sizes[0] / 128;  // 50000
    const int E = in_sizes[1] / 2;    // 800000
    const int* src = ei;
    const int* dst = ei + E;

    char* ws = (char*)d_ws;
    size_t off = 0;
    auto carve = [&](size_t bytes) {
        void* p = ws + off;
        off += (bytes + 255) & ~(size_t)255;
        return p;
    };
    int* deg       = (int*)carve((size_t)2 * N * 4);  // deg + cursor, one memset
    int* cursor    = deg + N;
    int* row_start = (int*)carve((size_t)N * 4);
    int* partials  = (int*)carve(256 * 4);
    int* csr_src   = (int*)carve((size_t)E * 4);
    unsigned short* xb   = (unsigned short*)carve((size_t)N * 128 * 2);
    unsigned short* aggb = (unsigned short*)carve((size_t)N * 128 * 2);
    unsigned short* hb   = (unsigned short*)carve((size_t)N * 128 * 2);
    unsigned short* P1l  = (unsigned short*)carve(128 * 128 * 2);
    unsigned short* P1r  = (unsigned short*)carve(128 * 128 * 2);
    unsigned short* P2l  = (unsigned short*)carve(128 * 64 * 2);
    unsigned short* P2r  = (unsigned short*)carve(128 * 64 * 2);

    hipMemsetAsync(deg, 0, (size_t)2 * N * 4, stream);

    const int nquad = N * 128 / 4;
    f32_to_bf16_kernel<<<(nquad + BLK - 1) / BLK, BLK, 0, stream>>>(x, xb, nquad);
    pack_all_w_kernel<<<192, BLK, 0, stream>>>(W1l, W1r, W2l, W2r, P1l, P1r, P2l, P2r);

    const int nchunk = (N + BLK - 1) / BLK;  // 196 (<=256)
    deg_count_kernel<<<(E + BLK - 1) / BLK, BLK, 0, stream>>>(dst, E, deg);
    partial_sum_kernel<<<nchunk, BLK, 0, stream>>>(deg, N, partials);
    scan_partials_kernel<<<1, BLK, 0, stream>>>(partials, nchunk);
    chunk_scan_kernel<<<nchunk, BLK, 0, stream>>>(deg, partials, N, row_start);

    const int range = (N + 7) / 8;          // 6250
    const int NCHUNKS = 512;
    const int CH = (E + NCHUNKS - 1) / NCHUNKS;
    fill_xcd_kernel<<<8 * NCHUNKS, BLK, 0, stream>>>(src, dst, E, row_start, cursor,
                                                     csr_src, range, CH);

    const int aggGrid = (N + 3) / 4;   // 1 node per wave, 4 waves/block
    const int gemmGrid = (N + 127) / 128;

    // layer 1: h = relu(agg(x)@W1l + b1 + x@W1r)   (bf16)
    agg_mlp_kernel<<<aggGrid, BLK, 0, stream>>>(xb, row_start, deg, csr_src, aggb, N, E);
    gemm_dual_kernel<128, true, true><<<gemmGrid, BLK, 0, stream>>>(aggb, xb, P1l, P1r, b1, hb, N);
    // layer 2: out = agg(h)@W2l + b2 + h@W2r       (f32)
    agg_mlp_kernel<<<aggGrid, BLK, 0, stream>>>(hb, row_start, deg, csr_src, aggb, N, E);
    gemm_dual_kernel<64, false, false><<<gemmGrid, BLK, 0, stream>>>(aggb, hb, P2l, P2r, b2, out, N);
}